// Round 8
// baseline (601.016 us; speedup 1.0000x reference)
//
#include <hip/hip_runtime.h>
#include <hip/hip_bf16.h>

#define NN 2048
#define KK 8
#define DD 32
#define ZSZ (KK * NN * DD)  // 524288
#define NCH 16              // m-chunks (grid = 32 n-blocks x 16 chunks = 512)
#define NSTEPS 4            // NN / NCH / 32
#define PSTR 20             // per-kp P row stride (u32)
#define NBLK 512

typedef __attribute__((ext_vector_type(8))) short short8;
typedef __attribute__((ext_vector_type(4))) float f32x4;
typedef __attribute__((ext_vector_type(4))) unsigned int u32x4;

union UU { u32x4 q; short8 v; unsigned int u[4]; };

#define SELHI 0x07060302u
#define SELLO 0x05040100u

__device__ __forceinline__ unsigned int prm(unsigned int a, unsigned int b, unsigned int sel) {
  return __builtin_amdgcn_perm(a, b, sel);
}
__device__ __forceinline__ unsigned int bfr(float x) {
  unsigned int u = __float_as_uint(x);
  return (u + 0x7fffu + ((u >> 16) & 1u)) >> 16;
}
__device__ __forceinline__ unsigned int packp(float a, float b) {  // a->lo16, b->hi16
  union { __hip_bfloat162 h; unsigned int u; } cv;
  cv.h = __float22bfloat162_rn(make_float2(a, b));
  return cv.u;
}
__device__ __forceinline__ f32x4 MF(short8 a, short8 b, f32x4 c) {
  return __builtin_amdgcn_mfma_f32_16x16x32_bf16(a, b, c, 0, 0, 0);
}
__device__ __forceinline__ short8 as_s8(u32x4 x) { UU u; u.q = x; return u.v; }
__device__ __forceinline__ int swz(int m) { return (m ^ (m >> 2)) & 3; }

// device-scope grid barrier: per-epoch counter (64B apart) + monotonically
// increasing flag. Requires all NBLK blocks co-resident (guaranteed:
// launch_bounds(256,2) + 52KB LDS -> >=2 blocks/CU, 512 <= 2*256).
__device__ __forceinline__ void gsync(unsigned int* bar, unsigned int ep) {
  __syncthreads();
  if (threadIdx.x == 0) {
    __threadfence();  // agent-scope release: write back this XCD's L2
    unsigned int old = __hip_atomic_fetch_add(&bar[16u * ep], 1u, __ATOMIC_ACQ_REL,
                                              __HIP_MEMORY_SCOPE_AGENT);
    unsigned int* flag = &bar[512];
    if (old == NBLK - 1u) {
      __hip_atomic_store(flag, ep + 1u, __ATOMIC_RELEASE, __HIP_MEMORY_SCOPE_AGENT);
    } else {
      while (__hip_atomic_load(flag, __ATOMIC_RELAXED, __HIP_MEMORY_SCOPE_AGENT) < ep + 1u)
        __builtin_amdgcn_s_sleep(4);
      __builtin_amdgcn_fence(__ATOMIC_ACQUIRE, "agent");  // invalidate stale L1/L2
    }
  }
  __syncthreads();
}

// One kernel: proj+mask | pack | (iter | reduce+pack)x3 | iter | output
__global__ __launch_bounds__(256, 2) void fused_kernel(
    const int* __restrict__ adj, const float* __restrict__ feat,
    const float* __restrict__ W, const float* __restrict__ bias,
    float* __restrict__ Z0, float* __restrict__ Z1,
    unsigned short* __restrict__ Zghi, unsigned short* __restrict__ Zthi,
    unsigned int* __restrict__ mbits, float* __restrict__ part,
    float* __restrict__ out, unsigned int* bar) {
  __shared__ __align__(16) unsigned int lds[8192 + 4 * 4 * 16 * PSTR];  // 53248 B
  const int t = threadIdx.x;
  const int bx = blockIdx.x;
  unsigned int ep = 0;

  // ================= phase P: projection (4 nodes/block) + adj bitmask =================
  {
    float* fsh = (float*)lds;
    const int nb = bx * 4;
#pragma unroll
    for (int i = 0; i < 2; ++i) fsh[t + 256 * i] = feat[nb * 128 + t + 256 * i];
    __syncthreads();
    const int k = t >> 5, c = t & 31;
    float s[4];
#pragma unroll
    for (int j = 0; j < 4; ++j) s[j] = bias[k * DD + c];
    const float* w = W + (k * 128) * DD + c;
#pragma unroll 8
    for (int d = 0; d < 128; ++d) {
      float wv = w[d * DD];
#pragma unroll
      for (int j = 0; j < 4; ++j) s[j] = fmaf(fsh[j * 128 + d], wv, s[j]);
    }
#pragma unroll
    for (int j = 0; j < 4; ++j) {
      float sq = s[j] * s[j];
#pragma unroll
      for (int off = 16; off > 0; off >>= 1) sq += __shfl_xor(sq, off, 32);
      Z0[(k * NN + nb + j) * DD + c] = s[j] / fmaxf(sqrtf(sq), 1e-12f);
    }
    const int lane = t & 63;
    for (int rr = 0; rr < 32; rr += 4) {
      int v[4];
#pragma unroll
      for (int j = 0; j < 4; ++j) v[j] = adj[bx * 8192 + (rr + j) * 256 + t];
#pragma unroll
      for (int j = 0; j < 4; ++j) {
        int idx = bx * 8192 + (rr + j) * 256 + t;
        unsigned long long bmask = __ballot(v[j] > 0);
        if (lane == 0) mbits[idx >> 5] = (unsigned int)bmask;
        if (lane == 32) mbits[idx >> 5] = (unsigned int)(bmask >> 32);
      }
    }
  }
  gsync(bar, ep++);

  // ---- rp phase body (reduce nc partials + l2norm + pack bf16 planes) ----
  auto rp_phase = [&](const float* Zin, int nc, float* Zout) {
    __syncthreads();
    unsigned short(*T)[33] = (unsigned short(*)[33])lds;
    const int k = bx >> 6, mt = bx & 63;
    const int m0 = mt * 32;
    const int mloc = t >> 3, c4 = t & 7;
    const size_t idx = (size_t)(k * NN + m0 + mloc) * DD + 4 * c4;
    float4 v = *(const float4*)&Zin[idx];
    for (int j = 0; j < nc; ++j) {
      float4 p = *(const float4*)&part[(size_t)j * ZSZ + idx];
      v.x += p.x; v.y += p.y; v.z += p.z; v.w += p.w;
    }
    float sq = v.x * v.x + v.y * v.y + v.z * v.z + v.w * v.w;
    sq += __shfl_xor(sq, 1, 8);
    sq += __shfl_xor(sq, 2, 8);
    sq += __shfl_xor(sq, 4, 8);
    const float sc = 1.0f / fmaxf(sqrtf(sq), 1e-12f);
    float z[4] = {v.x * sc, v.y * sc, v.z * sc, v.w * sc};
    if (nc) *(float4*)&Zout[idx] = make_float4(z[0], z[1], z[2], z[3]);
    unsigned int hi[4];
#pragma unroll
    for (int e = 0; e < 4; ++e) {
      hi[e] = bfr(z[e]);
      T[4 * c4 + e][mloc] = (unsigned short)hi[e];
    }
    *(uint2*)&Zghi[idx] = make_uint2(hi[0] | (hi[1] << 16), hi[2] | (hi[3] << 16));
    __syncthreads();
    const int cloc = t >> 3, m4 = t & 7;
    unsigned int o0 = (unsigned int)T[cloc][4 * m4 + 0] | ((unsigned int)T[cloc][4 * m4 + 1] << 16);
    unsigned int o1 = (unsigned int)T[cloc][4 * m4 + 2] | ((unsigned int)T[cloc][4 * m4 + 3] << 16);
    *(uint2*)&Zthi[(size_t)k * DD * NN + (size_t)cloc * NN + m0 + 4 * m4] = make_uint2(o0, o1);
  };

  // ================= phase R0: pack Z0 -> bf16 planes =================
  rp_phase(Z0, 0, Z1);
  gsync(bar, ep++);

  const float* zi = Z0;
  float* zo = Z1;

  for (int it = 0; it < 4; ++it) {
    // ================= phase I: gram + softmax(k) + aggregate =================
    {
      __syncthreads();
      const int w = t >> 6;
      const int lane = t & 63;
      const int l15 = lane & 15;
      const int g = lane >> 4;
      const int nw = (bx & 31) * 64 + w * 16;
      const int mchunk = (bx >> 5) * (NSTEPS * 32);

      const unsigned int* Zg = (const unsigned int*)Zghi;
      const unsigned int* Zt = (const unsigned int*)Zthi;

      short8 A[KK];
#pragma unroll
      for (int k = 0; k < KK; ++k)
        A[k] = as_s8(*(const u32x4*)&Zg[(size_t)(k * NN + nw + l15) * 16 + 4 * g]);

      f32x4 O[KK][2];
#pragma unroll
      for (int k = 0; k < KK; ++k)
#pragma unroll
        for (int ch = 0; ch < 2; ++ch) O[k][ch] = {0.0f, 0.0f, 0.0f, 0.0f};

      const int sqd = t & 3;
      const int sr0 = t >> 2;

      u32x4 Lgh[4], Lth[4];
      auto do_loads = [&](int mb) {
#pragma unroll
        for (int j = 0; j < 4; ++j) {
          int r = 64 * j + sr0;
          int k = r >> 5, rm = r & 31;
          Lgh[j] = *(const u32x4*)&Zg[(size_t)k * (NN * 16) + (size_t)(mb + rm) * 16 + sqd * 4];
          Lth[j] = *(const u32x4*)&Zt[(size_t)k * (NN * 16) + (size_t)rm * (NN / 2) + (mb >> 1) + sqd * 4];
        }
      };
      do_loads(mchunk);

      unsigned int* Pw = &lds[8192 + w * (4 * 16 * PSTR)];

      for (int st = 0; st < NSTEPS; ++st) {
        const int mb = mchunk + st * 32;
        __syncthreads();
#pragma unroll
        for (int j = 0; j < 4; ++j) {
          int r = 64 * j + sr0;
          int rm = r & 31;
          int qs = (sqd ^ swz(rm)) << 2;
          *(u32x4*)&lds[r * 16 + qs] = Lgh[j];
          *(u32x4*)&lds[4096 + r * 16 + qs] = Lth[j];
        }
        __syncthreads();
        if (st + 1 < NSTEPS) do_loads(mb + 32);

        f32x4 S[KK][2];
#pragma unroll
        for (int k = 0; k < KK; ++k) {
#pragma unroll
          for (int sub = 0; sub < 2; ++sub) {
            int m = 16 * sub + l15;
            u32x4 bh = *(const u32x4*)&lds[(k * 32 + m) * 16 + ((g ^ swz(m)) << 2)];
            f32x4 z = {0.0f, 0.0f, 0.0f, 0.0f};
            S[k][sub] = MF(A[k], as_s8(bh), z);
          }
        }

        unsigned int mw[4];
#pragma unroll
        for (int r = 0; r < 4; ++r) mw[r] = mbits[(size_t)(nw + 4 * g + r) * 64 + (mb >> 5)];
#pragma unroll
        for (int sub = 0; sub < 2; ++sub) {
#pragma unroll
          for (int r = 0; r < 4; ++r) {
            float e[KK];
            float sum = 0.0f;
#pragma unroll
            for (int k = 0; k < KK; ++k) { e[k] = __expf(S[k][sub][r]); sum += e[k]; }
            int ml = 16 * sub + l15;
            float f = ((mw[r] >> ml) & 1u) ? __builtin_amdgcn_rcpf(sum) : 0.0f;
#pragma unroll
            for (int k = 0; k < KK; ++k) S[k][sub][r] = e[k] * f;
          }
        }

#pragma unroll
        for (int kp = 0; kp < 4; ++kp)
#pragma unroll
          for (int sub = 0; sub < 2; ++sub)
#pragma unroll
            for (int r = 0; r < 4; ++r) {
              int n = 4 * g + r;
              Pw[kp * (16 * PSTR) + n * PSTR + 16 * sub + l15] =
                  packp(S[2 * kp][sub][r], S[2 * kp + 1][sub][r]);
            }

#pragma unroll
        for (int kp = 0; kp < 4; ++kp) {
          const unsigned int* Pr = &Pw[kp * (16 * PSTR) + l15 * PSTR + 8 * g];
          u32x4 a0 = *(const u32x4*)Pr;
          u32x4 a1 = *(const u32x4*)(Pr + 4);
          UU pk0, pk1;
          pk0.u[0] = prm(a0.y, a0.x, SELLO); pk0.u[1] = prm(a0.w, a0.z, SELLO);
          pk0.u[2] = prm(a1.y, a1.x, SELLO); pk0.u[3] = prm(a1.w, a1.z, SELLO);
          pk1.u[0] = prm(a0.y, a0.x, SELHI); pk1.u[1] = prm(a0.w, a0.z, SELHI);
          pk1.u[2] = prm(a1.y, a1.x, SELHI); pk1.u[3] = prm(a1.w, a1.z, SELHI);
#pragma unroll
          for (int kk = 0; kk < 2; ++kk) {
            int k = 2 * kp + kk;
#pragma unroll
            for (int ch = 0; ch < 2; ++ch) {
              int c = 16 * ch + l15;
              u32x4 b = *(const u32x4*)&lds[4096 + (k * 32 + c) * 16 + ((g ^ swz(c)) << 2)];
              O[k][ch] = MF(kk ? pk1.v : pk0.v, as_s8(b), O[k][ch]);
            }
          }
        }
      }

      float* dst = part + (size_t)(bx >> 5) * ZSZ;
#pragma unroll
      for (int k = 0; k < KK; ++k)
#pragma unroll
        for (int ch = 0; ch < 2; ++ch) {
          f32x4 o = O[k][ch];
#pragma unroll
          for (int r = 0; r < 4; ++r)
            dst[(size_t)(k * NN + nw + 4 * g + r) * DD + 16 * ch + l15] = o[r];
        }
    }
    gsync(bar, ep++);

    if (it < 3) {
      // ================= phase R: reduce + l2norm + repack =================
      rp_phase(zi, NCH, zo);
      gsync(bar, ep++);
      const float* tz = zi; zi = zo; zo = (float*)tz;
    } else {
      // ================= phase RO: reduce + l2norm + [N][K*D] output =================
      const int k = t >> 5, c = t & 31;
#pragma unroll
      for (int j = 0; j < 4; ++j) {
        const int n = bx * 4 + j;
        const size_t idx = (size_t)(k * NN + n) * DD + c;
        float v = zi[idx];
        for (int q = 0; q < NCH; ++q) v += part[(size_t)q * ZSZ + idx];
        float sq = v * v;
#pragma unroll
        for (int off = 16; off > 0; off >>= 1) sq += __shfl_xor(sq, off, 32);
        out[n * (KK * DD) + t] = v / fmaxf(sqrtf(sq), 1e-12f);
      }
    }
  }
}

extern "C" void kernel_launch(void* const* d_in, const int* in_sizes, int n_in,
                              void* d_out, int out_size, void* d_ws, size_t ws_size,
                              hipStream_t stream) {
  const int* adj = (const int*)d_in[0];
  const float* feat = (const float*)d_in[1];
  const float* W = (const float*)d_in[2];
  const float* b = (const float*)d_in[3];
  float* out = (float*)d_out;

  unsigned int* bar = (unsigned int*)d_ws;      // 4 KB barrier region
  float* Z0 = (float*)((char*)d_ws + 4096);
  float* Z1 = Z0 + ZSZ;
  unsigned short* Zghi = (unsigned short*)(Z1 + ZSZ);
  unsigned short* Zthi = Zghi + ZSZ;
  unsigned int* mbits = (unsigned int*)(Zthi + ZSZ);
  float* part = (float*)(mbits + NN * 64);

  hipMemsetAsync(bar, 0, 4096, stream);
  fused_kernel<<<NBLK, 256, 0, stream>>>(adj, feat, W, b, Z0, Z1, Zghi, Zthi,
                                         mbits, part, out, bar);
}

// Round 9
// 201.516 us; speedup vs baseline: 2.9825x; 2.9825x over previous
//
#include <hip/hip_runtime.h>
#include <hip/hip_bf16.h>

#define NN 2048
#define KK 8
#define DD 32
#define ZSZ (KK * NN * DD)  // 524288
#define PSTR 20             // per-kp P row stride (u32)

typedef __attribute__((ext_vector_type(8))) short short8;
typedef __attribute__((ext_vector_type(4))) float f32x4;
typedef __attribute__((ext_vector_type(4))) unsigned int u32x4;

union UU { u32x4 q; short8 v; unsigned int u[4]; };

#define SELHI 0x07060302u
#define SELLO 0x05040100u

__device__ __forceinline__ unsigned int prm(unsigned int a, unsigned int b, unsigned int sel) {
  return __builtin_amdgcn_perm(a, b, sel);
}
__device__ __forceinline__ unsigned int bfr(float x) {
  unsigned int u = __float_as_uint(x);
  return (u + 0x7fffu + ((u >> 16) & 1u)) >> 16;
}
__device__ __forceinline__ unsigned int packp(float a, float b) {  // a->lo16, b->hi16
  union { __hip_bfloat162 h; unsigned int u; } cv;
  cv.h = __float22bfloat162_rn(make_float2(a, b));
  return cv.u;
}
__device__ __forceinline__ f32x4 MF(short8 a, short8 b, f32x4 c) {
  return __builtin_amdgcn_mfma_f32_16x16x32_bf16(a, b, c, 0, 0, 0);
}
__device__ __forceinline__ short8 as_s8(u32x4 x) { UU u; u.q = x; return u.v; }
__device__ __forceinline__ int swz(int m) { return (m ^ (m >> 2)) & 3; }

// ------- merged: proj+l2norm+pack (blocks 0..256) + adj bitmask (blocks 256..4352) ----
// proj: block = 8 nodes, thread = (k,c). feat reads are wave-uniform -> scalar loads.
// W traffic: 128 KB/block * 256 blocks = 32 MB L2 (vs 1 GB in the 1-node/block version).
// Packs Zghi (coalesced rows) and Zthi (thread's 8 node-values are m-contiguous: uint4).
__global__ __launch_bounds__(256) void pm_kernel(const float* __restrict__ feat,
                                                 const float* __restrict__ W,
                                                 const float* __restrict__ bias,
                                                 float* __restrict__ Z,
                                                 unsigned short* __restrict__ Zghi,
                                                 unsigned short* __restrict__ Zthi,
                                                 const int* __restrict__ adj,
                                                 unsigned int* __restrict__ mbits) {
  const int t = threadIdx.x;
  if (blockIdx.x < 256) {
    const int nb = blockIdx.x * 8;
    const int k = t >> 5, c = t & 31;
    float s[8];
#pragma unroll
    for (int j = 0; j < 8; ++j) s[j] = bias[k * DD + c];
    const float* w = W + (k * 128) * DD + c;
    const float* fp = feat + nb * 128;  // uniform across block -> s_load
#pragma unroll 4
    for (int d = 0; d < 128; ++d) {
      float wv = w[d * DD];
#pragma unroll
      for (int j = 0; j < 8; ++j) s[j] = fmaf(fp[j * 128 + d], wv, s[j]);
    }
    unsigned int hi[8];
#pragma unroll
    for (int j = 0; j < 8; ++j) {
      float sq = s[j] * s[j];
#pragma unroll
      for (int off = 16; off > 0; off >>= 1) sq += __shfl_xor(sq, off, 32);
      float z = s[j] / fmaxf(sqrtf(sq), 1e-12f);
      Z[(k * NN + nb + j) * DD + c] = z;
      hi[j] = bfr(z);
      Zghi[(k * NN + nb + j) * DD + c] = (unsigned short)hi[j];
    }
    uint4 tp = make_uint4(hi[0] | (hi[1] << 16), hi[2] | (hi[3] << 16),
                          hi[4] | (hi[5] << 16), hi[6] | (hi[7] << 16));
    *(uint4*)&Zthi[(size_t)k * DD * NN + (size_t)c * NN + nb] = tp;
  } else {
    const int base = (blockIdx.x - 256) * 1024 + t;
    const int lane = t & 63;
    int v[4];
#pragma unroll
    for (int rr = 0; rr < 4; ++rr) v[rr] = adj[base + 256 * rr];
#pragma unroll
    for (int rr = 0; rr < 4; ++rr) {
      int idx = base + 256 * rr;
      unsigned long long b = __ballot(v[rr] > 0);
      if (lane == 0) mbits[idx >> 5] = (unsigned int)b;
      if (lane == 32) mbits[idx >> 5] = (unsigned int)(b >> 32);
    }
  }
}

// ------- fused: Z = l2norm(Zin + sum partials); write Z fp32 + hi plane + hi^T -------
__global__ __launch_bounds__(256) void rp_kernel(const float* __restrict__ Zin,
                                                 const float* __restrict__ part, int nc,
                                                 float* __restrict__ Zout,
                                                 unsigned short* __restrict__ Zghi,
                                                 unsigned short* __restrict__ Zthi) {
  __shared__ unsigned short T[DD][33];
  const int t = threadIdx.x;
  const int k = blockIdx.x >> 6, mt = blockIdx.x & 63;
  const int m0 = mt * 32;
  const int mloc = t >> 3, c4 = t & 7;
  const size_t idx = (size_t)(k * NN + m0 + mloc) * DD + 4 * c4;
  float4 v = *(const float4*)&Zin[idx];
  for (int j = 0; j < nc; ++j) {
    float4 p = *(const float4*)&part[(size_t)j * ZSZ + idx];
    v.x += p.x; v.y += p.y; v.z += p.z; v.w += p.w;
  }
  float sq = v.x * v.x + v.y * v.y + v.z * v.z + v.w * v.w;
  sq += __shfl_xor(sq, 1, 8);
  sq += __shfl_xor(sq, 2, 8);
  sq += __shfl_xor(sq, 4, 8);
  const float sc = 1.0f / fmaxf(sqrtf(sq), 1e-12f);
  float z[4] = {v.x * sc, v.y * sc, v.z * sc, v.w * sc};
  *(float4*)&Zout[idx] = make_float4(z[0], z[1], z[2], z[3]);
  unsigned int hi[4];
#pragma unroll
  for (int e = 0; e < 4; ++e) {
    hi[e] = bfr(z[e]);
    T[4 * c4 + e][mloc] = (unsigned short)hi[e];
  }
  *(uint2*)&Zghi[idx] = make_uint2(hi[0] | (hi[1] << 16), hi[2] | (hi[3] << 16));
  __syncthreads();
  const int cloc = t >> 3, m4 = t & 7;
  unsigned int o0 = (unsigned int)T[cloc][4 * m4 + 0] | ((unsigned int)T[cloc][4 * m4 + 1] << 16);
  unsigned int o1 = (unsigned int)T[cloc][4 * m4 + 2] | ((unsigned int)T[cloc][4 * m4 + 3] << 16);
  *(uint2*)&Zthi[(size_t)k * DD * NN + (size_t)cloc * NN + m0 + 4 * m4] = make_uint2(o0, o1);
}

// ---------------- fused MFMA iteration: gram + softmax(k) + aggregate ----------------
// grid (32 n-blocks, NC chunks), block 256 (4 waves x 16 n-rows)  [unchanged from R6]
__global__ __launch_bounds__(256, 2) void iter_kernel(const unsigned short* __restrict__ Zghi,
                                                      const unsigned short* __restrict__ Zthi,
                                                      const unsigned int* __restrict__ mbits,
                                                      float* __restrict__ part, int nsteps) {
  __shared__ __align__(16) unsigned int lds[8192 + 4 * 4 * 16 * PSTR];  // 52 KB
  const int t = threadIdx.x;
  const int w = t >> 6;
  const int lane = t & 63;
  const int l15 = lane & 15;
  const int g = lane >> 4;
  const int nw = blockIdx.x * 64 + w * 16;
  const int mchunk = blockIdx.y * (nsteps * 32);

  const unsigned int* Zg = (const unsigned int*)Zghi;
  const unsigned int* Zt = (const unsigned int*)Zthi;

  short8 A[KK];
#pragma unroll
  for (int k = 0; k < KK; ++k)
    A[k] = as_s8(*(const u32x4*)&Zg[(size_t)(k * NN + nw + l15) * 16 + 4 * g]);

  f32x4 O[KK][2];
#pragma unroll
  for (int k = 0; k < KK; ++k)
#pragma unroll
    for (int ch = 0; ch < 2; ++ch) O[k][ch] = {0.0f, 0.0f, 0.0f, 0.0f};

  const int sqd = t & 3;
  const int sr0 = t >> 2;

  u32x4 Lgh[4], Lth[4];
  auto do_loads = [&](int mb) {
#pragma unroll
    for (int j = 0; j < 4; ++j) {
      int r = 64 * j + sr0;
      int k = r >> 5, rm = r & 31;
      Lgh[j] = *(const u32x4*)&Zg[(size_t)k * (NN * 16) + (size_t)(mb + rm) * 16 + sqd * 4];
      Lth[j] = *(const u32x4*)&Zt[(size_t)k * (NN * 16) + (size_t)rm * (NN / 2) + (mb >> 1) + sqd * 4];
    }
  };
  do_loads(mchunk);

  unsigned int* Pw = &lds[8192 + w * (4 * 16 * PSTR)];

  for (int st = 0; st < nsteps; ++st) {
    const int mb = mchunk + st * 32;
    __syncthreads();
#pragma unroll
    for (int j = 0; j < 4; ++j) {
      int r = 64 * j + sr0;
      int rm = r & 31;
      int qs = (sqd ^ swz(rm)) << 2;
      *(u32x4*)&lds[r * 16 + qs] = Lgh[j];
      *(u32x4*)&lds[4096 + r * 16 + qs] = Lth[j];
    }
    __syncthreads();
    if (st + 1 < nsteps) do_loads(mb + 32);

    f32x4 S[KK][2];
#pragma unroll
    for (int k = 0; k < KK; ++k) {
#pragma unroll
      for (int sub = 0; sub < 2; ++sub) {
        int m = 16 * sub + l15;
        u32x4 bh = *(const u32x4*)&lds[(k * 32 + m) * 16 + ((g ^ swz(m)) << 2)];
        f32x4 z = {0.0f, 0.0f, 0.0f, 0.0f};
        S[k][sub] = MF(A[k], as_s8(bh), z);
      }
    }

    unsigned int mw[4];
#pragma unroll
    for (int r = 0; r < 4; ++r) mw[r] = mbits[(size_t)(nw + 4 * g + r) * 64 + (mb >> 5)];
#pragma unroll
    for (int sub = 0; sub < 2; ++sub) {
#pragma unroll
      for (int r = 0; r < 4; ++r) {
        float e[KK];
        float sum = 0.0f;
#pragma unroll
        for (int k = 0; k < KK; ++k) { e[k] = __expf(S[k][sub][r]); sum += e[k]; }
        int ml = 16 * sub + l15;
        float f = ((mw[r] >> ml) & 1u) ? __builtin_amdgcn_rcpf(sum) : 0.0f;
#pragma unroll
        for (int k = 0; k < KK; ++k) S[k][sub][r] = e[k] * f;
      }
    }

#pragma unroll
    for (int kp = 0; kp < 4; ++kp)
#pragma unroll
      for (int sub = 0; sub < 2; ++sub)
#pragma unroll
        for (int r = 0; r < 4; ++r) {
          int n = 4 * g + r;
          Pw[kp * (16 * PSTR) + n * PSTR + 16 * sub + l15] =
              packp(S[2 * kp][sub][r], S[2 * kp + 1][sub][r]);
        }

#pragma unroll
    for (int kp = 0; kp < 4; ++kp) {
      const unsigned int* Pr = &Pw[kp * (16 * PSTR) + l15 * PSTR + 8 * g];
      u32x4 a0 = *(const u32x4*)Pr;
      u32x4 a1 = *(const u32x4*)(Pr + 4);
      UU pk0, pk1;
      pk0.u[0] = prm(a0.y, a0.x, SELLO); pk0.u[1] = prm(a0.w, a0.z, SELLO);
      pk0.u[2] = prm(a1.y, a1.x, SELLO); pk0.u[3] = prm(a1.w, a1.z, SELLO);
      pk1.u[0] = prm(a0.y, a0.x, SELHI); pk1.u[1] = prm(a0.w, a0.z, SELHI);
      pk1.u[2] = prm(a1.y, a1.x, SELHI); pk1.u[3] = prm(a1.w, a1.z, SELHI);
#pragma unroll
      for (int kk = 0; kk < 2; ++kk) {
        int k = 2 * kp + kk;
#pragma unroll
        for (int ch = 0; ch < 2; ++ch) {
          int c = 16 * ch + l15;
          u32x4 b = *(const u32x4*)&lds[4096 + (k * 32 + c) * 16 + ((g ^ swz(c)) << 2)];
          O[k][ch] = MF(kk ? pk1.v : pk0.v, as_s8(b), O[k][ch]);
        }
      }
    }
  }

  float* dst = part + (size_t)blockIdx.y * ZSZ;
#pragma unroll
  for (int k = 0; k < KK; ++k)
#pragma unroll
    for (int ch = 0; ch < 2; ++ch) {
      f32x4 o = O[k][ch];
#pragma unroll
      for (int r = 0; r < 4; ++r)
        dst[(size_t)(k * NN + nw + 4 * g + r) * DD + 16 * ch + l15] = o[r];
    }
}

// ---------------- final: residual + reduce + l2norm + [N][K*D] output ----------------
__global__ __launch_bounds__(256) void ro_kernel(const float* __restrict__ Zin,
                                                 const float* __restrict__ part, int nc,
                                                 float* __restrict__ out) {
  const int n = blockIdx.x, t = threadIdx.x;
  const int k = t >> 5, c = t & 31;
  const size_t idx = (size_t)(k * NN + n) * DD + c;
  float v = Zin[idx];
  for (int j = 0; j < nc; ++j) v += part[(size_t)j * ZSZ + idx];
  float sq = v * v;
#pragma unroll
  for (int off = 16; off > 0; off >>= 1) sq += __shfl_xor(sq, off, 32);
  out[n * (KK * DD) + t] = v / fmaxf(sqrtf(sq), 1e-12f);
}

extern "C" void kernel_launch(void* const* d_in, const int* in_sizes, int n_in,
                              void* d_out, int out_size, void* d_ws, size_t ws_size,
                              hipStream_t stream) {
  const int* adj = (const int*)d_in[0];
  const float* feat = (const float*)d_in[1];
  const float* W = (const float*)d_in[2];
  const float* b = (const float*)d_in[3];
  float* out = (float*)d_out;

  int NC = 16;
  while (NC > 1) {
    size_t need = ((size_t)ZSZ * (2 + NC) + NN * 64) * 4 + (size_t)ZSZ * 2 * 2;
    if (need <= ws_size) break;
    NC >>= 1;
  }
  const int nsteps = NN / NC / 32;

  float* Z0 = (float*)d_ws;
  float* Z1 = Z0 + ZSZ;
  unsigned short* Zghi = (unsigned short*)(Z1 + ZSZ);
  unsigned short* Zthi = Zghi + ZSZ;
  unsigned int* mbits = (unsigned int*)(Zthi + ZSZ);
  float* part = (float*)(mbits + NN * 64);

  // proj + l2norm + bf16 pack + mask, one dispatch
  pm_kernel<<<256 + 4096, 256, 0, stream>>>(feat, W, b, Z0, Zghi, Zthi, adj, mbits);

  float* zi = Z0;
  float* zo = Z1;
  for (int it = 0; it < 4; ++it) {
    iter_kernel<<<dim3(32, NC), 256, 0, stream>>>(Zghi, Zthi, mbits, part, nsteps);
    if (it < 3) {
      rp_kernel<<<512, 256, 0, stream>>>(zi, part, NC, zo, Zghi, Zthi);
      float* tmp = zi; zi = zo; zo = tmp;
    } else {
      ro_kernel<<<NN, 256, 0, stream>>>(zi, part, NC, out);
    }
  }
}

// Round 10
// 199.432 us; speedup vs baseline: 3.0136x; 1.0105x over previous
//
#include <hip/hip_runtime.h>
#include <hip/hip_bf16.h>

#define NN 2048
#define KK 8
#define DD 32
#define ZSZ (KK * NN * DD)  // 524288
#define PSTR 20             // per-kp P row stride (u32)

typedef __attribute__((ext_vector_type(8))) short short8;
typedef __attribute__((ext_vector_type(4))) float f32x4;
typedef __attribute__((ext_vector_type(4))) unsigned int u32x4;

union UU { u32x4 q; short8 v; unsigned int u[4]; };

#define SELHI 0x07060302u
#define SELLO 0x05040100u

__device__ __forceinline__ unsigned int prm(unsigned int a, unsigned int b, unsigned int sel) {
  return __builtin_amdgcn_perm(a, b, sel);
}
__device__ __forceinline__ unsigned int bfr(float x) {
  unsigned int u = __float_as_uint(x);
  return (u + 0x7fffu + ((u >> 16) & 1u)) >> 16;
}
__device__ __forceinline__ unsigned int packp(float a, float b) {  // a->lo16, b->hi16
  union { __hip_bfloat162 h; unsigned int u; } cv;
  cv.h = __float22bfloat162_rn(make_float2(a, b));
  return cv.u;
}
__device__ __forceinline__ f32x4 MF(short8 a, short8 b, f32x4 c) {
  return __builtin_amdgcn_mfma_f32_16x16x32_bf16(a, b, c, 0, 0, 0);
}
__device__ __forceinline__ short8 as_s8(u32x4 x) { UU u; u.q = x; return u.v; }

// ------- merged: proj+l2norm+pack (blocks 0..256) + adj bitmask (blocks 256..4352) ----
__global__ __launch_bounds__(256) void pm_kernel(const float* __restrict__ feat,
                                                 const float* __restrict__ W,
                                                 const float* __restrict__ bias,
                                                 float* __restrict__ Z,
                                                 unsigned short* __restrict__ Zghi,
                                                 unsigned short* __restrict__ Zthi,
                                                 const int* __restrict__ adj,
                                                 unsigned int* __restrict__ mbits) {
  const int t = threadIdx.x;
  if (blockIdx.x < 256) {
    const int nb = blockIdx.x * 8;
    const int k = t >> 5, c = t & 31;
    float s[8];
#pragma unroll
    for (int j = 0; j < 8; ++j) s[j] = bias[k * DD + c];
    const float* w = W + (k * 128) * DD + c;
    const float* fp = feat + nb * 128;  // uniform across block -> s_load
#pragma unroll 4
    for (int d = 0; d < 128; ++d) {
      float wv = w[d * DD];
#pragma unroll
      for (int j = 0; j < 8; ++j) s[j] = fmaf(fp[j * 128 + d], wv, s[j]);
    }
    unsigned int hi[8];
#pragma unroll
    for (int j = 0; j < 8; ++j) {
      float sq = s[j] * s[j];
#pragma unroll
      for (int off = 16; off > 0; off >>= 1) sq += __shfl_xor(sq, off, 32);
      float z = s[j] / fmaxf(sqrtf(sq), 1e-12f);
      Z[(k * NN + nb + j) * DD + c] = z;
      hi[j] = bfr(z);
      Zghi[(k * NN + nb + j) * DD + c] = (unsigned short)hi[j];
    }
    uint4 tp = make_uint4(hi[0] | (hi[1] << 16), hi[2] | (hi[3] << 16),
                          hi[4] | (hi[5] << 16), hi[6] | (hi[7] << 16));
    *(uint4*)&Zthi[(size_t)k * DD * NN + (size_t)c * NN + nb] = tp;
  } else {
    const int base = (blockIdx.x - 256) * 1024 + t;
    const int lane = t & 63;
    int v[4];
#pragma unroll
    for (int rr = 0; rr < 4; ++rr) v[rr] = adj[base + 256 * rr];
#pragma unroll
    for (int rr = 0; rr < 4; ++rr) {
      int idx = base + 256 * rr;
      unsigned long long b = __ballot(v[rr] > 0);
      if (lane == 0) mbits[idx >> 5] = (unsigned int)b;
      if (lane == 32) mbits[idx >> 5] = (unsigned int)(b >> 32);
    }
  }
}

// ------- fused: Z = l2norm(Zin + sum partials); write Z fp32 + hi plane + hi^T -------
// NCt compile-time -> fully unrolled partial reduce (16 loads in flight)
template <int NCt>
__global__ __launch_bounds__(256) void rp_kernel(const float* __restrict__ Zin,
                                                 const float* __restrict__ part,
                                                 float* __restrict__ Zout,
                                                 unsigned short* __restrict__ Zghi,
                                                 unsigned short* __restrict__ Zthi) {
  __shared__ unsigned short T[DD][33];
  const int t = threadIdx.x;
  const int k = blockIdx.x >> 6, mt = blockIdx.x & 63;
  const int m0 = mt * 32;
  const int mloc = t >> 3, c4 = t & 7;
  const size_t idx = (size_t)(k * NN + m0 + mloc) * DD + 4 * c4;
  float4 v = *(const float4*)&Zin[idx];
#pragma unroll
  for (int j = 0; j < NCt; ++j) {
    float4 p = *(const float4*)&part[(size_t)j * ZSZ + idx];
    v.x += p.x; v.y += p.y; v.z += p.z; v.w += p.w;
  }
  float sq = v.x * v.x + v.y * v.y + v.z * v.z + v.w * v.w;
  sq += __shfl_xor(sq, 1, 8);
  sq += __shfl_xor(sq, 2, 8);
  sq += __shfl_xor(sq, 4, 8);
  const float sc = 1.0f / fmaxf(sqrtf(sq), 1e-12f);
  float z[4] = {v.x * sc, v.y * sc, v.z * sc, v.w * sc};
  *(float4*)&Zout[idx] = make_float4(z[0], z[1], z[2], z[3]);
  unsigned int hi[4];
#pragma unroll
  for (int e = 0; e < 4; ++e) {
    hi[e] = bfr(z[e]);
    T[4 * c4 + e][mloc] = (unsigned short)hi[e];
  }
  *(uint2*)&Zghi[idx] = make_uint2(hi[0] | (hi[1] << 16), hi[2] | (hi[3] << 16));
  __syncthreads();
  const int cloc = t >> 3, m4 = t & 7;
  unsigned int o0 = (unsigned int)T[cloc][4 * m4 + 0] | ((unsigned int)T[cloc][4 * m4 + 1] << 16);
  unsigned int o1 = (unsigned int)T[cloc][4 * m4 + 2] | ((unsigned int)T[cloc][4 * m4 + 3] << 16);
  *(uint2*)&Zthi[(size_t)k * DD * NN + (size_t)cloc * NN + m0 + 4 * m4] = make_uint2(o0, o1);
}

// ---------------- fused MFMA iteration: gram + softmax(k) + aggregate ----------------
// grid (32 n-blocks, NC chunks), block 256 (4 waves x 16 n-rows)
// Natural (unswizzled) tile layout: every b128 read/write pattern already lands
// exactly 8 lanes per bank-quad-group -> conflict-free. NS = steps, fully unrolled.
template <int NS>
__global__ __launch_bounds__(256, 2) void iter_kernel(const unsigned short* __restrict__ Zghi,
                                                      const unsigned short* __restrict__ Zthi,
                                                      const unsigned int* __restrict__ mbits,
                                                      float* __restrict__ part) {
  __shared__ __align__(16) unsigned int lds[8192 + 4 * 4 * 16 * PSTR];  // 52 KB
  const int t = threadIdx.x;
  const int w = t >> 6;
  const int lane = t & 63;
  const int l15 = lane & 15;
  const int g = lane >> 4;
  const int nw = blockIdx.x * 64 + w * 16;
  const int mchunk = blockIdx.y * (NS * 32);

  const unsigned int* Zg = (const unsigned int*)Zghi;
  const unsigned int* Zt = (const unsigned int*)Zthi;

  // persistent A-frags: A[k] = Zn[n=nw+l15][c=8g..8g+8)
  short8 A[KK];
#pragma unroll
  for (int k = 0; k < KK; ++k)
    A[k] = as_s8(*(const u32x4*)&Zg[(size_t)(k * NN + nw + l15) * 16 + 4 * g]);

  // preload the whole chunk's mask words: 4 rows x NS words, uint4 chunks
  unsigned int mwa[4][NS];
#pragma unroll
  for (int r = 0; r < 4; ++r)
#pragma unroll
    for (int q4 = 0; q4 < NS / 4; ++q4) {
      uint4 m4 = *(const uint4*)&mbits[(size_t)(nw + 4 * g + r) * 64 + (mchunk >> 5) + 4 * q4];
      mwa[r][4 * q4 + 0] = m4.x; mwa[r][4 * q4 + 1] = m4.y;
      mwa[r][4 * q4 + 2] = m4.z; mwa[r][4 * q4 + 3] = m4.w;
    }

  f32x4 O[KK][2];
#pragma unroll
  for (int k = 0; k < KK; ++k)
#pragma unroll
    for (int ch = 0; ch < 2; ++ch) O[k][ch] = {0.0f, 0.0f, 0.0f, 0.0f};

  // staging mapping: quad q fixed per thread, rows r = 64j + (t>>2)
  const int sqd = t & 3;
  const int sr0 = t >> 2;

  u32x4 Lgh[4], Lth[4];
  auto do_loads = [&](int mb) {
#pragma unroll
    for (int j = 0; j < 4; ++j) {
      int r = 64 * j + sr0;
      int k = r >> 5, rm = r & 31;
      Lgh[j] = *(const u32x4*)&Zg[(size_t)k * (NN * 16) + (size_t)(mb + rm) * 16 + sqd * 4];
      Lth[j] = *(const u32x4*)&Zt[(size_t)k * (NN * 16) + (size_t)rm * (NN / 2) + (mb >> 1) + sqd * 4];
    }
  };
  do_loads(mchunk);

  unsigned int* Pw = &lds[8192 + w * (4 * 16 * PSTR)];

#pragma unroll
  for (int st = 0; st < NS; ++st) {
    const int mb = mchunk + st * 32;
    __syncthreads();  // everyone done reading prev tiles
#pragma unroll
    for (int j = 0; j < 4; ++j) {
      int r = 64 * j + sr0;
      *(u32x4*)&lds[r * 16 + 4 * sqd] = Lgh[j];
      *(u32x4*)&lds[4096 + r * 16 + 4 * sqd] = Lth[j];
    }
    __syncthreads();
    if (st + 1 < NS) do_loads(mb + 32);

    // ---- per sub-tile: gram -> softmax -> P-write (pipelined across subs) ----
#pragma unroll
    for (int sub = 0; sub < 2; ++sub) {
      f32x4 S[KK];
#pragma unroll
      for (int k = 0; k < KK; ++k) {
        int m = 16 * sub + l15;
        u32x4 bh = *(const u32x4*)&lds[(k * 32 + m) * 16 + 4 * g];
        f32x4 z = {0.0f, 0.0f, 0.0f, 0.0f};
        S[k] = MF(A[k], as_s8(bh), z);
      }
#pragma unroll
      for (int r = 0; r < 4; ++r) {
        float e[KK];
        float sum = 0.0f;
#pragma unroll
        for (int k = 0; k < KK; ++k) { e[k] = __expf(S[k][r]); sum += e[k]; }
        int ml = 16 * sub + l15;
        float f = ((mwa[r][st] >> ml) & 1u) ? __builtin_amdgcn_rcpf(sum) : 0.0f;
#pragma unroll
        for (int k = 0; k < KK; ++k) S[k][r] = e[k] * f;
      }
#pragma unroll
      for (int kp = 0; kp < 4; ++kp)
#pragma unroll
        for (int r = 0; r < 4; ++r) {
          int n = 4 * g + r;
          Pw[kp * (16 * PSTR) + n * PSTR + 16 * sub + l15] =
              packp(S[2 * kp][r], S[2 * kp + 1][r]);
        }
    }

    // ---- per k-pair: P read-back (C->A transpose), aggregate from tho tile ----
#pragma unroll
    for (int kp = 0; kp < 4; ++kp) {
      const unsigned int* Pr = &Pw[kp * (16 * PSTR) + l15 * PSTR + 8 * g];
      u32x4 a0 = *(const u32x4*)Pr;
      u32x4 a1 = *(const u32x4*)(Pr + 4);
      UU pk0, pk1;
      pk0.u[0] = prm(a0.y, a0.x, SELLO); pk0.u[1] = prm(a0.w, a0.z, SELLO);
      pk0.u[2] = prm(a1.y, a1.x, SELLO); pk0.u[3] = prm(a1.w, a1.z, SELLO);
      pk1.u[0] = prm(a0.y, a0.x, SELHI); pk1.u[1] = prm(a0.w, a0.z, SELHI);
      pk1.u[2] = prm(a1.y, a1.x, SELHI); pk1.u[3] = prm(a1.w, a1.z, SELHI);
#pragma unroll
      for (int kk = 0; kk < 2; ++kk) {
        int k = 2 * kp + kk;
#pragma unroll
        for (int ch = 0; ch < 2; ++ch) {
          int c = 16 * ch + l15;
          u32x4 b = *(const u32x4*)&lds[4096 + (k * 32 + c) * 16 + 4 * g];
          O[k][ch] = MF(kk ? pk1.v : pk0.v, as_s8(b), O[k][ch]);
        }
      }
    }
  }

  // ---- write partials: part[chunk][k][n][c] ----
  float* dst = part + (size_t)blockIdx.y * ZSZ;
#pragma unroll
  for (int k = 0; k < KK; ++k)
#pragma unroll
    for (int ch = 0; ch < 2; ++ch) {
      f32x4 o = O[k][ch];
#pragma unroll
      for (int r = 0; r < 4; ++r)
        dst[(size_t)(k * NN + nw + 4 * g + r) * DD + 16 * ch + l15] = o[r];
    }
}

// ---------------- final: residual + reduce + l2norm + [N][K*D] output ----------------
template <int NCt>
__global__ __launch_bounds__(256) void ro_kernel(const float* __restrict__ Zin,
                                                 const float* __restrict__ part,
                                                 float* __restrict__ out) {
  const int n = blockIdx.x, t = threadIdx.x;
  const int k = t >> 5, c = t & 31;
  const size_t idx = (size_t)(k * NN + n) * DD + c;
  float v = Zin[idx];
#pragma unroll
  for (int j = 0; j < NCt; ++j) v += part[(size_t)j * ZSZ + idx];
  float sq = v * v;
#pragma unroll
  for (int off = 16; off > 0; off >>= 1) sq += __shfl_xor(sq, off, 32);
  out[n * (KK * DD) + t] = v / fmaxf(sqrtf(sq), 1e-12f);
}

extern "C" void kernel_launch(void* const* d_in, const int* in_sizes, int n_in,
                              void* d_out, int out_size, void* d_ws, size_t ws_size,
                              hipStream_t stream) {
  const int* adj = (const int*)d_in[0];
  const float* feat = (const float*)d_in[1];
  const float* W = (const float*)d_in[2];
  const float* b = (const float*)d_in[3];
  float* out = (float*)d_out;

  int NC = 16;
  while (NC > 4) {
    size_t need = ((size_t)ZSZ * (2 + NC) + NN * 64) * 4 + (size_t)ZSZ * 2 * 2;
    if (need <= ws_size) break;
    NC >>= 1;
  }

  float* Z0 = (float*)d_ws;
  float* Z1 = Z0 + ZSZ;
  unsigned short* Zghi = (unsigned short*)(Z1 + ZSZ);
  unsigned short* Zthi = Zghi + ZSZ;
  unsigned int* mbits = (unsigned int*)(Zthi + ZSZ);
  float* part = (float*)(mbits + NN * 64);

  pm_kernel<<<256 + 4096, 256, 0, stream>>>(feat, W, b, Z0, Zghi, Zthi, adj, mbits);

  float* zi = Z0;
  float* zo = Z1;
  for (int it = 0; it < 4; ++it) {
    if (NC == 16)
      iter_kernel<4><<<dim3(32, 16), 256, 0, stream>>>(Zghi, Zthi, mbits, part);
    else if (NC == 8)
      iter_kernel<8><<<dim3(32, 8), 256, 0, stream>>>(Zghi, Zthi, mbits, part);
    else
      iter_kernel<16><<<dim3(32, 4), 256, 0, stream>>>(Zghi, Zthi, mbits, part);
    if (it < 3) {
      if (NC == 16)
        rp_kernel<16><<<512, 256, 0, stream>>>(zi, part, zo, Zghi, Zthi);
      else if (NC == 8)
        rp_kernel<8><<<512, 256, 0, stream>>>(zi, part, zo, Zghi, Zthi);
      else
        rp_kernel<4><<<512, 256, 0, stream>>>(zi, part, zo, Zghi, Zthi);
      float* tmp = zi; zi = zo; zo = tmp;
    } else {
      if (NC == 16)
        ro_kernel<16><<<NN, 256, 0, stream>>>(zi, part, out);
      else if (NC == 8)
        ro_kernel<8><<<NN, 256, 0, stream>>>(zi, part, out);
      else
        ro_kernel<4><<<NN, 256, 0, stream>>>(zi, part, out);
    }
  }
}